// Round 5
// baseline (114.489 us; speedup 1.0000x reference)
//
#include <hip/hip_runtime.h>
#include <hip/hip_bf16.h>

#define NPTS 384
#define NN (NPTS * NPTS)
#define DIMS 256
#define IT 8                  // i's per main-kernel block
#define NZI (NPTS / IT)       // 48 i-chunks

// ---------------------------------------------------------------------------
// Kernel 1: fused Gram + derive, one 32x32 tile per block.
// Block (16,16,4): z-slice kc computes a K=64 chunk of the 2x2 micro-tile
// (identical per-thread chain to R4's gram_part -> same TLP: 288 blocks x 16
// waves = 4608 waves ~ 4.5/SIMD), then LDS-reduce the 4 partials in-block and
// run the epilogue — no partials round-trip through global, no second kernel.
// Outputs per matrix:  G[i][j] = e_i.e_j
//                      UH[i][j] = {u, h} = {1/max(||e_i-e_j||,eps) (0 on diag),
//                                           G_ii/2 - G_ij}
// Row sqnorms computed in-block (64 rows, 4 float4/thread).
// ---------------------------------------------------------------------------
__global__ __launch_bounds__(1024) void gram_fused_kernel(
        const float* __restrict__ Es, const float* __restrict__ Et,
        float* __restrict__ Gs, float* __restrict__ Gt,
        float2* __restrict__ UHs, float2* __restrict__ UHt,
        float* __restrict__ out) {
    const int z = blockIdx.z;
    const float* __restrict__ E  = z ? Et : Es;
    float*       __restrict__ G  = z ? Gt : Gs;
    float2*      __restrict__ UH = z ? UHt : UHs;

    const int tx = threadIdx.x;          // 0..15
    const int ty = threadIdx.y;          // 0..15
    const int kc = threadIdx.z;          // 0..3 (K chunk)
    const int t  = kc * 256 + ty * 16 + tx;
    const int i0 = blockIdx.x * 32;
    const int j0 = blockIdx.y * 32;

    if (blockIdx.x == 0 && blockIdx.y == 0 && z == 0 && t == 0) out[0] = 0.0f;

    __shared__ float sn[64];
    __shared__ float red[4][1024];       // [kc][(ty*16+tx)*4 + q]

    // --- row squared-norms: 64 rows (32 i-side, 32 j-side), 16 thr/row ---
    {
        const int r = t >> 4;            // 0..63
        const int p = t & 15;            // 16 threads per row
        const int row = (r < 32) ? (i0 + r) : (j0 + r - 32);
        const float4* __restrict__ src = (const float4*)(E + row * DIMS) + p * 4;
        float s = 0.f;
#pragma unroll
        for (int q = 0; q < 4; q++) {
            const float4 v = src[q];
            s += v.x * v.x + v.y * v.y + v.z * v.z + v.w * v.w;
        }
        s += __shfl_xor(s, 1, 64);
        s += __shfl_xor(s, 2, 64);
        s += __shfl_xor(s, 4, 64);
        s += __shfl_xor(s, 8, 64);
        if (p == 0) sn[r] = s;
    }

    // --- Gram 2x2 micro-tile over this slice's K=64 chunk ---
    const int i = i0 + 2 * ty;
    const int j = j0 + 2 * tx;
    const float4* __restrict__ a0 = (const float4*)(E + i * DIMS + kc * 64);
    const float4* __restrict__ a1 = (const float4*)(E + (i + 1) * DIMS + kc * 64);
    const float4* __restrict__ b0 = (const float4*)(E + j * DIMS + kc * 64);
    const float4* __restrict__ b1 = (const float4*)(E + (j + 1) * DIMS + kc * 64);

    float g00 = 0.f, g01 = 0.f, g10 = 0.f, g11 = 0.f;
#pragma unroll 4
    for (int k = 0; k < 16; k++) {
        const float4 av0 = a0[k], av1 = a1[k], bv0 = b0[k], bv1 = b1[k];
        g00 = fmaf(av0.x, bv0.x, g00); g00 = fmaf(av0.y, bv0.y, g00);
        g00 = fmaf(av0.z, bv0.z, g00); g00 = fmaf(av0.w, bv0.w, g00);
        g01 = fmaf(av0.x, bv1.x, g01); g01 = fmaf(av0.y, bv1.y, g01);
        g01 = fmaf(av0.z, bv1.z, g01); g01 = fmaf(av0.w, bv1.w, g01);
        g10 = fmaf(av1.x, bv0.x, g10); g10 = fmaf(av1.y, bv0.y, g10);
        g10 = fmaf(av1.z, bv0.z, g10); g10 = fmaf(av1.w, bv0.w, g10);
        g11 = fmaf(av1.x, bv1.x, g11); g11 = fmaf(av1.y, bv1.y, g11);
        g11 = fmaf(av1.z, bv1.z, g11); g11 = fmaf(av1.w, bv1.w, g11);
    }

    const int t2 = ty * 16 + tx;
    *(float4*)&red[kc][t2 * 4] = make_float4(g00, g01, g10, g11);
    __syncthreads();

    if (kc == 0) {
        const float4 r0 = *(const float4*)&red[0][t2 * 4];
        const float4 r1 = *(const float4*)&red[1][t2 * 4];
        const float4 r2 = *(const float4*)&red[2][t2 * 4];
        const float4 r3 = *(const float4*)&red[3][t2 * 4];
        const float g[2][2] = {{r0.x + r1.x + r2.x + r3.x, r0.y + r1.y + r2.y + r3.y},
                               {r0.z + r1.z + r2.z + r3.z, r0.w + r1.w + r2.w + r3.w}};
        const float si[2] = {sn[2 * ty], sn[2 * ty + 1]};
        const float sj[2] = {sn[32 + 2 * tx], sn[32 + 2 * tx + 1]};

#pragma unroll
        for (int r = 0; r < 2; r++) {
            const int ii = i + r;
            float uh[4];
#pragma unroll
            for (int c = 0; c < 2; c++) {
                const int jj = j + c;
                const float gv = g[r][c];
                const float v  = si[r] + sj[c] - 2.0f * gv;
                const float n  = sqrtf(fmaxf(v, 0.0f));
                uh[2 * c]     = (ii == jj) ? 0.0f : (1.0f / fmaxf(n, 1e-12f));
                uh[2 * c + 1] = 0.5f * si[r] - gv;
            }
            *(float2*)(G + ii * NPTS + j) = make_float2(g[r][0], g[r][1]);
            *(float4*)(UH + ii * NPTS + j) = make_float4(uh[0], uh[1], uh[2], uh[3]);
        }
    }
}

// ---------------------------------------------------------------------------
// Kernel 2: main reduction over triangular (jt<=kt) 64x64 tile set.
//   angle_ijk = u_ij * u_ik * (G_jk + h_ij + h_ik)
//   smooth_l1(d) = 0.5 * med3(d*d, 2|d|-1, 1)
// 16x16 threads, 4x4 micro-tile, IT=8 i's per block (1008 blocks ~3.9 w/SIMD).
// Register software-pipeline: prefetch next-i's 8 float4 while computing.
// (bit-identical math to R4 — absmax was 0.0)
// ---------------------------------------------------------------------------
__global__ __launch_bounds__(256, 3) void rkd_main_kernel(
        const float* __restrict__ Gs, const float* __restrict__ Gt,
        const float2* __restrict__ UHs, const float2* __restrict__ UHt,
        float* __restrict__ out) {
    const int tlin = blockIdx.x;
    const int kt = (int)((sqrtf(8.0f * (float)tlin + 1.0f) - 1.0f) * 0.5f);
    const int jt = tlin - (kt * (kt + 1)) / 2;

    const int tx = threadIdx.x;    // k-dim
    const int ty = threadIdx.y;    // j-dim
    const int jb = jt * 64 + 4 * ty;
    const int kb = kt * 64 + 4 * tx;
    const int ibase = blockIdx.y * IT;

    float gs[4][4], gt[4][4];
#pragma unroll
    for (int a = 0; a < 4; a++) {
        const float4 vs = *(const float4*)(Gs + (jb + a) * NPTS + kb);
        const float4 vt = *(const float4*)(Gt + (jb + a) * NPTS + kb);
        gs[a][0] = vs.x; gs[a][1] = vs.y; gs[a][2] = vs.z; gs[a][3] = vs.w;
        gt[a][0] = vt.x; gt[a][1] = vt.y; gt[a][2] = vt.z; gt[a][3] = vt.w;
    }

    const float4* __restrict__ pjs = (const float4*)(UHs + (size_t)ibase * NPTS + jb);
    const float4* __restrict__ pjt = (const float4*)(UHt + (size_t)ibase * NPTS + jb);
    const float4* __restrict__ pks = (const float4*)(UHs + (size_t)ibase * NPTS + kb);
    const float4* __restrict__ pkt = (const float4*)(UHt + (size_t)ibase * NPTS + kb);

    const bool offd = (jt != kt);
    float wh[4][4];
#pragma unroll
    for (int a = 0; a < 4; a++)
#pragma unroll
        for (int b = 0; b < 4; b++) {
            const int jj = jb + a, kk = kb + b;
            wh[a][b] = (kk > jj) ? 1.0f : ((kk == jj) ? 0.5f : 0.0f);
        }

    float4 L[8];
    L[0] = pjs[0]; L[1] = pjs[1];
    L[2] = pjt[0]; L[3] = pjt[1];
    L[4] = pks[0]; L[5] = pks[1];
    L[6] = pkt[0]; L[7] = pkt[1];

    float acc = 0.0f;
#pragma unroll 2
    for (int iz = 0; iz < IT; iz++) {
        const int nz = (iz + 1 < IT) ? iz + 1 : iz;
        const int ro = nz * (NPTS / 2);
        float4 Ln[8];
        Ln[0] = pjs[ro];     Ln[1] = pjs[ro + 1];
        Ln[2] = pjt[ro];     Ln[3] = pjt[ro + 1];
        Ln[4] = pks[ro];     Ln[5] = pks[ro + 1];
        Ln[6] = pkt[ro];     Ln[7] = pkt[ro + 1];

        const float u_sj[4] = {L[0].x, L[0].z, L[1].x, L[1].z};
        const float h_sj[4] = {L[0].y, L[0].w, L[1].y, L[1].w};
        const float u_tj[4] = {L[2].x, L[2].z, L[3].x, L[3].z};
        const float h_tj[4] = {L[2].y, L[2].w, L[3].y, L[3].w};
        const float u_sk[4] = {L[4].x, L[4].z, L[5].x, L[5].z};
        const float h_sk[4] = {L[4].y, L[4].w, L[5].y, L[5].w};
        const float u_tk[4] = {L[6].x, L[6].z, L[7].x, L[7].z};
        const float h_tk[4] = {L[6].y, L[6].w, L[7].y, L[7].w};

        if (offd) {
#pragma unroll
            for (int a = 0; a < 4; a++) {
                const float usa = u_sj[a], hsa = h_sj[a];
                const float uta = u_tj[a], hta = h_tj[a];
#pragma unroll
                for (int b = 0; b < 4; b++) {
                    const float ts = gs[a][b] + hsa + h_sk[b];
                    const float tt = gt[a][b] + hta + h_tk[b];
                    const float ps = usa * u_sk[b];
                    const float pt = uta * u_tk[b];
                    const float mt = pt * tt;
                    const float d  = fmaf(ps, ts, -mt);
                    const float q  = d * d;
                    const float w  = fmaf(2.0f, fabsf(d), -1.0f);
                    acc += __builtin_amdgcn_fmed3f(q, w, 1.0f);
                }
            }
        } else {
#pragma unroll
            for (int a = 0; a < 4; a++) {
                const float usa = u_sj[a], hsa = h_sj[a];
                const float uta = u_tj[a], hta = h_tj[a];
#pragma unroll
                for (int b = 0; b < 4; b++) {
                    const float ts = gs[a][b] + hsa + h_sk[b];
                    const float tt = gt[a][b] + hta + h_tk[b];
                    const float ps = usa * u_sk[b];
                    const float pt = uta * u_tk[b];
                    const float mt = pt * tt;
                    const float d  = fmaf(ps, ts, -mt);
                    const float q  = d * d;
                    const float w  = fmaf(2.0f, fabsf(d), -1.0f);
                    const float l  = __builtin_amdgcn_fmed3f(q, w, 1.0f);
                    acc = fmaf(wh[a][b], l, acc);
                }
            }
        }

#pragma unroll
        for (int r = 0; r < 8; r++) L[r] = Ln[r];
    }

#pragma unroll
    for (int off = 32; off > 0; off >>= 1)
        acc += __shfl_down(acc, off, 64);

    __shared__ float wsum[4];
    const int tid  = ty * 16 + tx;
    const int wid  = tid >> 6;
    const int lane = tid & 63;
    if (lane == 0) wsum[wid] = acc;
    __syncthreads();
    if (tid == 0) {
        const float s = wsum[0] + wsum[1] + wsum[2] + wsum[3];
        atomicAdd(out, s * (1.0f / (384.0f * 384.0f * 384.0f)));
    }
}

extern "C" void kernel_launch(void* const* d_in, const int* in_sizes, int n_in,
                              void* d_out, int out_size, void* d_ws, size_t ws_size,
                              hipStream_t stream) {
    const float* student = (const float*)d_in[0];
    const float* teacher = (const float*)d_in[1];
    float* out = (float*)d_out;

    // ws layout (floats): Gs[NN], Gt[NN], UHs[2*NN], UHt[2*NN]
    float*  Gs  = (float*)d_ws;
    float*  Gt  = Gs + NN;
    float2* UHs = (float2*)(Gt + NN);
    float2* UHt = UHs + NN;

    gram_fused_kernel<<<dim3(NPTS / 32, NPTS / 32, 2), dim3(16, 16, 4), 0, stream>>>(
        student, teacher, Gs, Gt, UHs, UHt, out);

    rkd_main_kernel<<<dim3(21, NZI), dim3(16, 16), 0, stream>>>(
        Gs, Gt, UHs, UHt, out);
}